// Round 5
// baseline (209.339 us; speedup 1.0000x reference)
//
#include <hip/hip_runtime.h>
#include <math.h>
#include <stdint.h>

// Problem constants (static per reference):
//   B=32, N_ATOMS=128, C=25 (rep 2,2,0), RADIUS=8, MAX_NEIGHBORS=32
#define NATOMS   128
#define NCELLS   25
#define NCAND    (NATOMS * NCELLS)   // 3200 candidates per center atom
#define MAXNB    32
#define R2       64.0f
#define BLK      256
#define KEYCAP   256

// d2 chain replicated exactly as the reference (no FMA contraction):
// dv = (pos_j - pos_i) + off ; d2 = (dx*dx + dy*dy) + dz*dz
__device__ __forceinline__ float d2_exact(float4 p, float4 ctr, float4 o) {
    float dx = __fadd_rn(__fsub_rn(p.x, ctr.x), o.x);
    float dy = __fadd_rn(__fsub_rn(p.y, ctr.y), o.y);
    float dz = __fadd_rn(__fsub_rn(p.z, ctr.z), o.z);
    return __fadd_rn(__fadd_rn(__fmul_rn(dx,dx), __fmul_rn(dy,dy)),
                     __fmul_rn(dz,dz));
}

// ---------------- Kernel 1: selection (one block per center atom) -----------
// Computes the exact stable 32-NN cutoff key (d2 bits << 32 | flat f, matching
// jnp stable argsort tie-break) -> ws_K[bi]; accumulates clamped per-image
// neighbor counts into out_nb (pre-zeroed; <=4096/image so f32 atomics exact).
// No s_d2, no big outputs: the key pass recomputes d2 (bit-identical chain).
__global__ __launch_bounds__(BLK) void select_kernel(
    const float* __restrict__ pos, const float* __restrict__ cell,
    unsigned long long* __restrict__ ws_K, float* __restrict__ out_nb)
{
    __shared__ float4 s_pos4[NATOMS];
    __shared__ float4 s_off4[NCELLS];
    __shared__ unsigned s_hist[256];
    __shared__ unsigned s_wtot[4];
    __shared__ int s_wred[4];
    __shared__ unsigned long long s_keys[KEYCAP];
    __shared__ unsigned s_cnt;
    __shared__ int s_binsel, s_need, s_tot, s_att;
    __shared__ unsigned long long s_K;

    const int bi   = blockIdx.x;       // b*128 + i
    const int b    = bi >> 7;
    const int i    = bi & 127;
    const int tid  = threadIdx.x;
    const int lane = tid & 63;
    const int w    = tid >> 6;

    if (tid < NATOMS) {
        const float* p = pos + (b * NATOMS + tid) * 3;
        s_pos4[tid] = make_float4(p[0], p[1], p[2], 0.0f);
    }
    if (tid >= 160 && tid < 160 + NCELLS) {
        int c = tid - 160;
        float ux = (float)(c / 5 - 2);
        float uy = (float)(c % 5 - 2);
        // off = ux*row0 + uy*row1; products exact (|u|<=2), one rounded add.
        float ox = __fadd_rn(__fmul_rn(ux, cell[b*9+0]), __fmul_rn(uy, cell[b*9+3]));
        float oy = __fadd_rn(__fmul_rn(ux, cell[b*9+1]), __fmul_rn(uy, cell[b*9+4]));
        float oz = __fadd_rn(__fmul_rn(ux, cell[b*9+2]), __fmul_rn(uy, cell[b*9+5]));
        s_off4[c] = make_float4(ox, oy, oz, 0.0f);
    }
    s_hist[tid] = 0u;
    if (tid == 0) { s_cnt = 0; s_binsel = -1; s_need = 0; s_att = 0; s_K = ~0ULL; }
    __syncthreads();

    const float4 ctr = s_pos4[i];

    // pass 1: within count + fine histogram of d2 in [0,16)
    // (32nd NN sits at d2 ~ 2.6 at this density)
    int local = 0;
    for (int g = tid; g < NCAND; g += BLK) {
        int c = g >> 7;            // wave-uniform: s_off4 broadcast
        int j = g & 127;
        float d2 = d2_exact(s_pos4[j], ctr, s_off4[c]);
        bool within = (d2 <= R2) && (d2 > 1e-4f);
        if (within) {
            local++;
            if (d2 < 16.0f)
                atomicAdd(&s_hist[(int)(d2 * 16.0f)], 1u);
        }
    }
    for (int o = 32; o; o >>= 1) local += __shfl_down(local, o);
    if (lane == 0) s_wred[w] = local;
    __syncthreads();
    if (tid == 0) {
        int tot = s_wred[0] + s_wred[1] + s_wred[2] + s_wred[3];
        s_tot = tot;
        atomicAdd(&out_nb[b], (float)(tot < MAXNB ? tot : MAXNB));
    }
    __syncthreads();

    if (s_tot > MAXNB) {
        // critical bin: attempt 0 = [0,16) fine (prebuilt); attempt 1 = full range
        for (int att = 0; att < 2 && s_binsel < 0; att++) {
            if (att == 1) {        // rare path: rebuild full-range histogram
                s_hist[tid] = 0u;
                __syncthreads();
                for (int g = tid; g < NCAND; g += BLK) {
                    int c = g >> 7, j = g & 127;
                    float d2 = d2_exact(s_pos4[j], ctr, s_off4[c]);
                    if ((d2 <= R2) && (d2 > 1e-4f)) {
                        int bin = (int)(d2 * 4.0f);
                        if (bin > 255) bin = 255;
                        atomicAdd(&s_hist[bin], 1u);
                    }
                }
                __syncthreads();
            }
            // wave-shuffle inclusive scan of 256 bins (4 waves x 64 bins)
            unsigned h = s_hist[tid];
            int v = (int)h;
            #pragma unroll
            for (int off = 1; off < 64; off <<= 1) {
                int u = __shfl_up(v, off, 64);
                if (lane >= off) v += u;
            }
            if (lane == 63) s_wtot[w] = (unsigned)v;
            __syncthreads();
            unsigned pre = 0;
            for (int ww = 0; ww < w; ww++) pre += s_wtot[ww];
            unsigned htot = s_wtot[0] + s_wtot[1] + s_wtot[2] + s_wtot[3];
            unsigned ci = (unsigned)v + pre, ce = ci - h;
            if (htot >= MAXNB && h > 0 && ce < MAXNB && ci >= MAXNB) {
                s_binsel = tid;
                s_need   = MAXNB - (int)ce;
                s_att    = att;
            }
            __syncthreads();
        }

        // exact cutoff key inside the critical bin (recompute d2, same chain)
        const int   binsel = s_binsel;
        const float sc  = s_att ? 4.0f  : 16.0f;
        const float lim = s_att ? 64.5f : 16.0f;
        for (int g = tid; g < NCAND; g += BLK) {
            int c = g >> 7, j = g & 127;
            float d2 = d2_exact(s_pos4[j], ctr, s_off4[c]);
            bool within = (d2 <= R2) && (d2 > 1e-4f);   // excludes self (bin 0!)
            if (within && d2 < lim) {
                int bin = (int)(d2 * sc);
                if (bin > 255) bin = 255;
                if (bin == binsel) {
                    unsigned idx = atomicAdd(&s_cnt, 1u);
                    if (idx < KEYCAP)
                        s_keys[idx] =
                            ((unsigned long long)__float_as_uint(d2) << 32)
                            | (unsigned)(j * NCELLS + c);
                }
            }
        }
        __syncthreads();
        const int m = (int)s_cnt, need = s_need;
        if (m <= KEYCAP) {
            for (int p = tid; p < m; p += BLK) {
                unsigned long long kp = s_keys[p];
                int r = 0;
                for (int q = 0; q < m; q++) r += (s_keys[q] < kp);
                if (r == need - 1) s_K = kp;   // keys distinct -> unique
            }
        } else {
            // never-expected overflow fallback: rank critical-bin members by
            // full recompute (O(NCAND) per member; members are few)
            for (int g = tid; g < NCAND; g += BLK) {
                int c = g >> 7, j = g & 127;
                float d2 = d2_exact(s_pos4[j], ctr, s_off4[c]);
                bool within = (d2 <= R2) && (d2 > 1e-4f);
                if (!within || d2 >= lim) continue;
                int bin = (int)(d2 * sc);
                if (bin > 255) bin = 255;
                if (bin != binsel) continue;
                unsigned long long kf =
                    ((unsigned long long)__float_as_uint(d2) << 32)
                    | (unsigned)(j * NCELLS + c);
                int r = 0;
                for (int q = 0; q < NCAND; q++) {
                    int cq = q >> 7, jq = q & 127;
                    float dq = d2_exact(s_pos4[jq], ctr, s_off4[cq]);
                    bool wq = (dq <= R2) && (dq > 1e-4f);
                    if (!wq || dq >= lim) continue;
                    int bq = (int)(dq * sc);
                    if (bq > 255) bq = 255;
                    if (bq != binsel) continue;
                    unsigned long long kq =
                        ((unsigned long long)__float_as_uint(dq) << 32)
                        | (unsigned)(jq * NCELLS + cq);
                    r += (kq < kf);
                }
                if (r == need - 1) s_K = kf;
            }
        }
        __syncthreads();
    }
    if (tid == 0) ws_K[bi] = s_K;
}

// ---------------- Kernel 2: pure streaming writer ---------------------------
// 2 blocks per center (half = 1600 candidates = 400 float4 groups). One
// barrier after staging, then recompute d2 (bit-identical) + stream float4
// stores. Structurally a fill: stores flow from ~200 cycles in, no atomics.
__global__ __launch_bounds__(BLK) void write_kernel(
    const float* __restrict__ pos, const float* __restrict__ cell,
    const unsigned long long* __restrict__ ws_K,
    float* __restrict__ out_dist, float* __restrict__ out_ctype,
    float* __restrict__ out_mask)
{
    __shared__ float4 s_pos4[NATOMS];
    __shared__ float4 s_off4[NCELLS];
    __shared__ float  s_ct[NCELLS];

    const int bx   = blockIdx.x;
    const int bi   = bx >> 1;          // center atom
    const int half = bx & 1;
    const int b    = bi >> 7;
    const int i    = bi & 127;
    const int tid  = threadIdx.x;

    if (tid < NATOMS) {
        const float* p = pos + (b * NATOMS + tid) * 3;
        s_pos4[tid] = make_float4(p[0], p[1], p[2], 0.0f);
    }
    if (tid >= 160 && tid < 160 + NCELLS) {
        int c = tid - 160;
        float ux = (float)(c / 5 - 2);
        float uy = (float)(c % 5 - 2);
        float ox = __fadd_rn(__fmul_rn(ux, cell[b*9+0]), __fmul_rn(uy, cell[b*9+3]));
        float oy = __fadd_rn(__fmul_rn(ux, cell[b*9+1]), __fmul_rn(uy, cell[b*9+4]));
        float oz = __fadd_rn(__fmul_rn(ux, cell[b*9+2]), __fmul_rn(uy, cell[b*9+5]));
        s_off4[c] = make_float4(ox, oy, oz, 0.0f);
        // ct = (ux+2)*5 + (uy+2)*5 (mults=[5,5,1] quirk per reference)
        s_ct[c] = (float)(5 * (c / 5) + 5 * (c % 5));
    }
    __syncthreads();

    const unsigned long long K = ws_K[bi];   // uniform (scalar) load
    const float4 ctr = s_pos4[i];

    const long long gbase = (long long)bi * (NCAND / 4) + half * 400;
    float4* o0 = (float4*)out_dist  + gbase;
    float4* o1 = (float4*)out_ctype + gbase;
    float4* o2 = (float4*)out_mask  + gbase;

    // 400 groups per half; half*1600 is a multiple of 25 -> j,c decompose cleanly
    for (int g = tid; g < 400; g += BLK) {
        int f0 = g * 4;                 // within-half flat index
        int j  = (half << 6) + f0 / 25; // half*64 + ...
        int c  = f0 - (f0 / 25) * 25;
        int fa = half * 1600 + f0;      // absolute flat index (tie-break key)
        float4 r0, r1, r2;
        #pragma unroll
        for (int e = 0; e < 4; e++) {
            float d2 = d2_exact(s_pos4[j], ctr, s_off4[c]);
            bool within = (d2 <= R2) && (d2 > 1e-4f);
            unsigned long long key =
                ((unsigned long long)__float_as_uint(d2) << 32)
                | (unsigned)(fa + e);
            bool keep = within && (key <= K);
            (&r0.x)[e] = keep ? sqrtf(d2) : 0.0f;
            (&r1.x)[e] = keep ? s_ct[c] : 0.0f;
            (&r2.x)[e] = keep ? 1.0f : 0.0f;
            c++; if (c == NCELLS) { c = 0; j++; }
        }
        o0[g] = r0; o1[g] = r1; o2[g] = r2;
    }
}

extern "C" void kernel_launch(void* const* d_in, const int* in_sizes, int n_in,
                              void* d_out, int out_size, void* d_ws, size_t ws_size,
                              hipStream_t stream) {
    const float* pos  = (const float*)d_in[0];   // [32,128,3]
    const float* cell = (const float*)d_in[1];   // [32,3,3]
    float* out = (float*)d_out;
    const long long E = 32LL * NATOMS * NATOMS * NCELLS;   // 13,107,200
    float* out_dist  = out;
    float* out_ct    = out + E;
    float* out_mask  = out + 2 * E;
    float* out_nb    = out + 3 * E;                         // 32 floats
    unsigned long long* ws_K = (unsigned long long*)d_ws;   // 4096 x u64

    // zero per-image counters (d_out poisoned 0xAA); exact f32 atomic sums
    hipMemsetAsync(out_nb, 0, 32 * sizeof(float), stream);
    hipLaunchKernelGGL(select_kernel, dim3(32 * NATOMS), dim3(BLK), 0, stream,
                       pos, cell, ws_K, out_nb);
    hipLaunchKernelGGL(write_kernel, dim3(32 * NATOMS * 2), dim3(BLK), 0, stream,
                       pos, cell, ws_K, out_dist, out_ct, out_mask);
}